// Round 5
// baseline (318.094 us; speedup 1.0000x reference)
//
#include <hip/hip_runtime.h>

// DigiCaps dynamic routing — MFMA recompute, software-pipelined.
// inputs [512,1152,8] f32, W [10,1152,16,8] f32, out v [512,10,16] f32.
// u_hat[b,j,i,d] = sum_k x[b,i,k] W[j,i,d,k]; logits b_t = u_hat . vsum
// (vsum = running sum of v's) so u_hat is never materialized.
//
// mfma_f32_16x16x32_bf16, C-layout: lane&15 = b(col), (lane>>4)*4+reg = d(row).
// MODE 0 (uniform c): K packed with 4 i's (full K=32), pure MFMA chain.
// MODE 1 (routing): per-i MFMA (K=8 + zero-pad), register-double-buffered
// A/x frags -> one batched 11-load prefetch per t, no per-j vmcnt stalls.

#define NB 512
#define NI 1152
#define NJ 10
#define ND 16

typedef short  bf16x8 __attribute__((ext_vector_type(8)));
typedef float  f32x4  __attribute__((ext_vector_type(4)));

constexpr int   NBG  = 32;   // b-groups of 16
constexpr int   NIGB = 18;   // i-group blocks; 4 wave-slices each
constexpr int   SL   = 16;   // i's per wave-slice (72 slices total)
constexpr int   NPT  = 18;   // partials per b (one per block-ig)
constexpr float EPS_ = 1e-7f;

constexpr size_t XB_ELEMS = (size_t)NB * NI * 8;       // bf16
constexpr size_t WB_ELEMS = (size_t)NJ * NI * ND * 8;  // bf16

__device__ inline unsigned short f2bf(float f) {  // RNE f32 -> bf16
    unsigned u = __float_as_uint(f);
    return (unsigned short)((u + 0x7fffu + ((u >> 16) & 1u)) >> 16);
}

__global__ __launch_bounds__(256)
void conv_bf16(const float* __restrict__ src, unsigned short* __restrict__ dst,
               int n4, int zpad)
{
    int t = blockIdx.x * 256 + threadIdx.x;
    if (t < n4) {
        float4 v = ((const float4*)src)[t];
        ushort4 o;
        o.x = f2bf(v.x); o.y = f2bf(v.y); o.z = f2bf(v.z); o.w = f2bf(v.w);
        ((ushort4*)dst)[t] = o;
    }
    if (zpad && t == 0) {
        ushort4 z; z.x = z.y = z.z = z.w = 0;
        ((ushort4*)dst)[n4]     = z;
        ((ushort4*)dst)[n4 + 1] = z;
    }
}

template <int MODE>
__global__ __launch_bounds__(256)
void caps_pass(const unsigned short* __restrict__ xb,
               const unsigned short* __restrict__ wb,
               const unsigned short* __restrict__ zpad,
               const float* __restrict__ vsum_g,
               float* __restrict__ part)
{
    __shared__ float s_red[16 * 160];

    const int tid = threadIdx.x, lane = tid & 63, w = tid >> 6;
    const int bl = lane & 15, kg = lane >> 4;
    const int bg = blockIdx.x, igb = blockIdx.y;
    const int b  = bg * 16 + bl;
    const int i0 = (igb * 4 + w) * SL;   // this wave's 16-i slice

    for (int k = tid; k < 2560; k += 256) s_red[k] = 0.f;

    const f32x4 zero = {0.f, 0.f, 0.f, 0.f};
    f32x4 sacc[NJ];
#pragma unroll
    for (int j = 0; j < NJ; ++j) sacc[j] = zero;

    if (MODE == 0) {
        // ---- full-K GEMM: K = (4 i's) x (8 k). A k-group = i-offset.
        // A lane (kg,bl): W[j, i0+4t+kg, d=bl, 0:8]  (64 lanes -> 1KB contig/j)
        // B lane (kg,bl): x[b=bl's b, i0+4t+kg, 0:8]
        const unsigned short* xpt = xb + ((size_t)b * NI + i0 + kg) * 8;
        const unsigned short* wpt = wb + ((size_t)(i0 + kg)) * 128 + bl * 8;
#pragma unroll
        for (int t = 0; t < SL / 4; ++t) {
            bf16x8 bf = *(const bf16x8*)(xpt + t * 32);
#pragma unroll
            for (int j = 0; j < NJ; ++j) {
                bf16x8 af = *(const bf16x8*)(wpt + (size_t)j * NI * 128 + t * 512);
                sacc[j] = __builtin_amdgcn_mfma_f32_16x16x32_bf16(af, bf, sacc[j], 0, 0, 0);
            }
        }
    } else {
        // ---- routing pass: per-i u_hat, software-pipelined frag loads.
        f32x4 vs[NJ];
#pragma unroll
        for (int j = 0; j < NJ; ++j)
            vs[j] = *(const f32x4*)(vsum_g + (size_t)b * 160 + j * 16 + kg * 4);

        const unsigned short* xrow = xb + ((size_t)b * NI + i0) * 8;
        const unsigned short* wrow = (kg == 0) ? (wb + (size_t)i0 * 128 + bl * 8) : zpad;
        const size_t jstr = (kg == 0) ? (size_t)NI * 128 : 0;
        const size_t istp = (kg == 0) ? 128 : 0;

        bf16x8 af[2][NJ];
        bf16x8 xf[2];
        xf[0] = *(const bf16x8*)xrow;
#pragma unroll
        for (int j = 0; j < NJ; ++j)
            af[0][j] = *(const bf16x8*)(wrow + j * jstr);

#pragma unroll 2
        for (int t = 0; t < SL; ++t) {
            const int cur = t & 1, nxt = cur ^ 1;
            if (t + 1 < SL) {   // batched prefetch for t+1 (11 loads, no waits)
                xf[nxt] = *(const bf16x8*)(xrow + (t + 1) * 8);
#pragma unroll
                for (int j = 0; j < NJ; ++j)
                    af[nxt][j] = *(const bf16x8*)(wrow + (size_t)(t + 1) * istp + j * jstr);
            }

            f32x4 uh[NJ];
#pragma unroll
            for (int j = 0; j < NJ; ++j)
                uh[j] = __builtin_amdgcn_mfma_f32_16x16x32_bf16(af[cur][j], xf[cur], zero, 0, 0, 0);

            float bd[NJ];
#pragma unroll
            for (int j = 0; j < NJ; ++j) {
                float v = uh[j][0] * vs[j][0] + uh[j][1] * vs[j][1]
                        + uh[j][2] * vs[j][2] + uh[j][3] * vs[j][3];
                v += __shfl_xor(v, 16, 64);   // reduce the 4 d-quads
                v += __shfl_xor(v, 32, 64);
                bd[j] = v;
            }
            float m = bd[0];
#pragma unroll
            for (int j = 1; j < NJ; ++j) m = fmaxf(m, bd[j]);
            float Z = 0.f;
#pragma unroll
            for (int j = 0; j < NJ; ++j) { bd[j] = __expf(bd[j] - m); Z += bd[j]; }
            const float rZ = 1.f / Z;
#pragma unroll
            for (int j = 0; j < NJ; ++j) {
                const float c = bd[j] * rZ;
                sacc[j] += c * uh[j];
            }
        }
    }

    // ---- cross-wave reduce (4 waves, same b-tile, different i-slices)
    __syncthreads();
    const int base = bl * 160 + kg * 4;
#pragma unroll
    for (int j = 0; j < NJ; ++j)
#pragma unroll
        for (int r = 0; r < 4; ++r)
            atomicAdd(&s_red[base + j * 16 + r], sacc[j][r]);
    __syncthreads();

    float* pp = part + ((size_t)igb * NB + bg * 16) * 160;
    for (int k = tid; k < 2560; k += 256) pp[k] = s_red[k];
}

// Sum NPT i-group partials, scale, squash over d (16-lane shfl), update vsum/out.
__global__ __launch_bounds__(256)
void squash_reduce(const float* __restrict__ part, float* __restrict__ vsum_g,
                   float* __restrict__ out, float alpha, int mode)
{
    const int t = blockIdx.x * 256 + threadIdx.x;   // < 81920 = b*160 + j*16 + d
    const float* p = part + t;
    float a0 = 0.f, a1 = 0.f, a2 = 0.f;
#pragma unroll
    for (int ig = 0; ig < NPT; ig += 3) {
        a0 += p[(size_t)ig * 81920];
        a1 += p[(size_t)(ig + 1) * 81920];
        a2 += p[(size_t)(ig + 2) * 81920];
    }
    const float s = (a0 + a1 + a2) * alpha;

    float sq = s * s;
    sq += __shfl_xor(sq, 1, 64);
    sq += __shfl_xor(sq, 2, 64);
    sq += __shfl_xor(sq, 4, 64);
    sq += __shfl_xor(sq, 8, 64);
    const float sc = sq / ((1.f + sq) * sqrtf(sq + EPS_));
    const float v  = sc * s;

    if (mode == 0)      vsum_g[t] = v;
    else if (mode == 1) vsum_g[t] += v;
    else                out[t] = v;
}

extern "C" void kernel_launch(void* const* d_in, const int* in_sizes, int n_in,
                              void* d_out, int out_size, void* d_ws, size_t ws_size,
                              hipStream_t stream)
{
    const float* inp = (const float*)d_in[0];
    const float* Wg  = (const float*)d_in[1];
    float* out = (float*)d_out;

    unsigned short* xbp = (unsigned short*)d_ws;
    unsigned short* wbp = xbp + XB_ELEMS;
    unsigned short* zp  = wbp + WB_ELEMS;
    float* part = (float*)((char*)d_ws + (XB_ELEMS + WB_ELEMS + 8) * 2);
    float* vsum = part + (size_t)NPT * NB * 160;

    conv_bf16<<<4608, 256, 0, stream>>>(inp, xbp, 1179648, 0);
    conv_bf16<<<1440, 256, 0, stream>>>(Wg,  wbp,  368640, 1);

    dim3 grid(NBG, NIGB);   // (32,18) = 576 blocks, 4 wave-slices each
    // iter 0: c uniform 1/10 (folded into alpha)
    caps_pass<0><<<grid, 256, 0, stream>>>(xbp, wbp, zp, nullptr, part);
    squash_reduce<<<320, 256, 0, stream>>>(part, vsum, out, 0.1f, 0);
    // iter 1: logits = u_hat . v0
    caps_pass<1><<<grid, 256, 0, stream>>>(xbp, wbp, zp, vsum, part);
    squash_reduce<<<320, 256, 0, stream>>>(part, vsum, out, 1.0f, 1);
    // iter 2: logits = u_hat . (v0+v1)
    caps_pass<1><<<grid, 256, 0, stream>>>(xbp, wbp, zp, vsum, part);
    squash_reduce<<<320, 256, 0, stream>>>(part, vsum, out, 1.0f, 2);
}

// Round 6
// 286.221 us; speedup vs baseline: 1.1114x; 1.1114x over previous
//
#include <hip/hip_runtime.h>

// DigiCaps dynamic routing — MFMA recompute, register-fixed.
// inputs [512,1152,8] f32, W [10,1152,16,8] f32, out v [512,10,16] f32.
// u_hat[b,j,i,d] = sum_k x[b,i,k] W[j,i,d,k]; logits b_t = u_hat . vsum
// (vsum = running sum of v's) so u_hat is never materialized.
//
// mfma_f32_16x16x32_bf16, C-layout: lane&15 = b(col), (lane>>4)*4+reg = d(row).
// ROUND 6 KEY FIX: __launch_bounds__(256, 2). With the bare (256) bound the
// compiler allocated only 80-136 VGPRs against a ~190-reg demand -> scratch
// spills in the t-loop (L2-resident, invisible in FETCH_SIZE, ~serialized
// VMEM latency per t) -> R4/R5's 73-107us latency-bound passes. (256,2)
// caps at 256 VGPRs, fits the whole working set, 2 blocks/CU on a 512-block
// grid. j-loop split into batched load-all -> mfma-all (one waitcnt per t).

#define NB 512
#define NI 1152
#define NJ 10
#define ND 16

typedef short  bf16x8 __attribute__((ext_vector_type(8)));
typedef float  f32x4  __attribute__((ext_vector_type(4)));

constexpr int   NBG  = 32;   // b-groups of 16
constexpr int   NIG  = 16;   // i-group blocks (72 i each; 18 per wave)
constexpr int   IPW  = 18;   // i's per wave
constexpr float EPS_ = 1e-7f;

constexpr size_t XB_ELEMS = (size_t)NB * NI * 8;       // bf16
constexpr size_t WB_ELEMS = (size_t)NJ * NI * ND * 8;  // bf16
constexpr int    XQ = 1179648;                         // x float4 quads
constexpr int    WQ = 368640;                          // W float4 quads

__device__ inline unsigned short f2bf(float f) {  // RNE f32 -> bf16
    unsigned u = __float_as_uint(f);
    return (unsigned short)((u + 0x7fffu + ((u >> 16) & 1u)) >> 16);
}

// Single fused conversion kernel: x then W then the 8-element zero pad.
__global__ __launch_bounds__(256)
void conv_bf16(const float* __restrict__ x, const float* __restrict__ Wg,
               unsigned short* __restrict__ xb, unsigned short* __restrict__ wb)
{
    int t = blockIdx.x * 256 + threadIdx.x;
    if (t < XQ) {
        float4 v = ((const float4*)x)[t];
        ushort4 o;
        o.x = f2bf(v.x); o.y = f2bf(v.y); o.z = f2bf(v.z); o.w = f2bf(v.w);
        ((ushort4*)xb)[t] = o;
    } else if (t - XQ < WQ) {
        int u = t - XQ;
        float4 v = ((const float4*)Wg)[u];
        ushort4 o;
        o.x = f2bf(v.x); o.y = f2bf(v.y); o.z = f2bf(v.z); o.w = f2bf(v.w);
        ((ushort4*)wb)[u] = o;
    } else if (t - XQ - WQ < 2) {
        ushort4 z; z.x = z.y = z.z = z.w = 0;
        ((ushort4*)wb)[WQ + (t - XQ - WQ)] = z;
    }
}

template <int MODE>
__global__ __launch_bounds__(256, 2)
void caps_pass(const unsigned short* __restrict__ xb,
               const unsigned short* __restrict__ wb,
               const unsigned short* __restrict__ zpad,
               const float* __restrict__ vsum_g,
               float* __restrict__ part)
{
    __shared__ float s_red[16 * 160];

    const int tid = threadIdx.x, lane = tid & 63, w = tid >> 6;
    const int bl = lane & 15, kg = lane >> 4;
    const int bg = blockIdx.x, ig = blockIdx.y;
    const int b  = bg * 16 + bl;
    const int i0 = ig * 72 + w * IPW;

    for (int k = tid; k < 2560; k += 256) s_red[k] = 0.f;

    const f32x4 zero = {0.f, 0.f, 0.f, 0.f};
    f32x4 sacc[NJ];
#pragma unroll
    for (int j = 0; j < NJ; ++j) sacc[j] = zero;

    if (MODE == 0) {
        // ---- uniform-c pass: K packed with 4 i's (full K=32). A k-group = i-offset.
        const unsigned short* xpt = xb + ((size_t)b * NI + i0 + kg) * 8;
        const unsigned short* wpt = wb + ((size_t)(i0 + kg)) * 128 + bl * 8;
#pragma unroll
        for (int t = 0; t < 4; ++t) {           // i0 .. i0+15
            bf16x8 af[NJ];
#pragma unroll
            for (int j = 0; j < NJ; ++j)
                af[j] = *(const bf16x8*)(wpt + (size_t)j * NI * 128 + t * 512);
            bf16x8 bf = *(const bf16x8*)(xpt + t * 32);
#pragma unroll
            for (int j = 0; j < NJ; ++j)
                sacc[j] = __builtin_amdgcn_mfma_f32_16x16x32_bf16(af[j], bf, sacc[j], 0, 0, 0);
        }
        {   // tail: i0+16, i0+17 (kg 0,1 real; kg 2,3 read zero A)
            const unsigned short* wt = (kg < 2)
                ? (wb + (size_t)(i0 + 16 + kg) * 128 + bl * 8) : zpad;
            const size_t jstr = (kg < 2) ? (size_t)NI * 128 : 0;
            bf16x8 af[NJ];
#pragma unroll
            for (int j = 0; j < NJ; ++j)
                af[j] = *(const bf16x8*)(wt + j * jstr);
            bf16x8 bf = *(const bf16x8*)(xb + ((size_t)b * NI + i0 + 16 + (kg & 1)) * 8);
#pragma unroll
            for (int j = 0; j < NJ; ++j)
                sacc[j] = __builtin_amdgcn_mfma_f32_16x16x32_bf16(af[j], bf, sacc[j], 0, 0, 0);
        }
    } else {
        // ---- routing pass: per-i u_hat (K=8 + zero-pad), batched frag loads.
        f32x4 vs[NJ];
#pragma unroll
        for (int j = 0; j < NJ; ++j)
            vs[j] = *(const f32x4*)(vsum_g + (size_t)b * 160 + j * 16 + kg * 4);

        const unsigned short* xrow = xb + ((size_t)b * NI + i0) * 8;
        const unsigned short* wrow = (kg == 0) ? (wb + (size_t)i0 * 128 + bl * 8) : zpad;
        const size_t jstr = (kg == 0) ? (size_t)NI * 128 : 0;
        const size_t istp = (kg == 0) ? 128 : 0;

#pragma unroll 2
        for (int t = 0; t < IPW; ++t) {
            // batched: 10 A-frag + 1 B-frag loads issue together, one wait.
            bf16x8 af[NJ];
            const unsigned short* wr = wrow + (size_t)t * istp;
#pragma unroll
            for (int j = 0; j < NJ; ++j)
                af[j] = *(const bf16x8*)(wr + j * jstr);
            bf16x8 xf = *(const bf16x8*)(xrow + t * 8);

            f32x4 uh[NJ];
#pragma unroll
            for (int j = 0; j < NJ; ++j)
                uh[j] = __builtin_amdgcn_mfma_f32_16x16x32_bf16(af[j], xf, zero, 0, 0, 0);

            float bd[NJ];
#pragma unroll
            for (int j = 0; j < NJ; ++j) {
                float v = uh[j][0] * vs[j][0] + uh[j][1] * vs[j][1]
                        + uh[j][2] * vs[j][2] + uh[j][3] * vs[j][3];
                v += __shfl_xor(v, 16, 64);   // reduce the 4 d-quads
                v += __shfl_xor(v, 32, 64);
                bd[j] = v;
            }
            float m = bd[0];
#pragma unroll
            for (int j = 1; j < NJ; ++j) m = fmaxf(m, bd[j]);
            float Z = 0.f;
#pragma unroll
            for (int j = 0; j < NJ; ++j) { bd[j] = __expf(bd[j] - m); Z += bd[j]; }
            const float rZ = 1.f / Z;
#pragma unroll
            for (int j = 0; j < NJ; ++j) {
                const float c = bd[j] * rZ;
                sacc[j] += c * uh[j];
            }
        }
    }

    // ---- cross-wave reduce (4 waves, same b-tile, different i-slices)
    __syncthreads();
    const int base = bl * 160 + kg * 4;
#pragma unroll
    for (int j = 0; j < NJ; ++j)
#pragma unroll
        for (int r = 0; r < 4; ++r)
            atomicAdd(&s_red[base + j * 16 + r], sacc[j][r]);
    __syncthreads();

    float* pp = part + ((size_t)ig * NB + bg * 16) * 160;
    for (int k = tid; k < 2560; k += 256) pp[k] = s_red[k];
}

// Sum NIG i-group partials, scale, squash over d (16-lane shfl), update vsum/out.
__global__ __launch_bounds__(256)
void squash_reduce(const float* __restrict__ part, float* __restrict__ vsum_g,
                   float* __restrict__ out, float alpha, int mode)
{
    const int t = blockIdx.x * 256 + threadIdx.x;   // < 81920 = b*160 + j*16 + d
    const float* p = part + t;
    float a0 = 0.f, a1 = 0.f, a2 = 0.f, a3 = 0.f;
#pragma unroll
    for (int ig = 0; ig < NIG; ig += 4) {
        a0 += p[(size_t)ig * 81920];
        a1 += p[(size_t)(ig + 1) * 81920];
        a2 += p[(size_t)(ig + 2) * 81920];
        a3 += p[(size_t)(ig + 3) * 81920];
    }
    const float s = ((a0 + a1) + (a2 + a3)) * alpha;

    float sq = s * s;
    sq += __shfl_xor(sq, 1, 64);
    sq += __shfl_xor(sq, 2, 64);
    sq += __shfl_xor(sq, 4, 64);
    sq += __shfl_xor(sq, 8, 64);
    const float sc = sq / ((1.f + sq) * sqrtf(sq + EPS_));
    const float v  = sc * s;

    if (mode == 0)      vsum_g[t] = v;
    else if (mode == 1) vsum_g[t] += v;
    else                out[t] = v;
}

extern "C" void kernel_launch(void* const* d_in, const int* in_sizes, int n_in,
                              void* d_out, int out_size, void* d_ws, size_t ws_size,
                              hipStream_t stream)
{
    const float* inp = (const float*)d_in[0];
    const float* Wg  = (const float*)d_in[1];
    float* out = (float*)d_out;

    unsigned short* xbp = (unsigned short*)d_ws;
    unsigned short* wbp = xbp + XB_ELEMS;
    unsigned short* zp  = wbp + WB_ELEMS;
    float* part = (float*)((char*)d_ws + (XB_ELEMS + WB_ELEMS + 8) * 2);
    float* vsum = part + (size_t)NIG * NB * 160;

    conv_bf16<<<(XQ + WQ + 2 + 255) / 256, 256, 0, stream>>>(inp, Wg, xbp, wbp);

    dim3 grid(NBG, NIG);   // (32,16) = 512 blocks = exactly 2/CU
    // iter 0: c uniform 1/10 (folded into alpha)
    caps_pass<0><<<grid, 256, 0, stream>>>(xbp, wbp, zp, nullptr, part);
    squash_reduce<<<320, 256, 0, stream>>>(part, vsum, out, 0.1f, 0);
    // iter 1: logits = u_hat . v0
    caps_pass<1><<<grid, 256, 0, stream>>>(xbp, wbp, zp, vsum, part);
    squash_reduce<<<320, 256, 0, stream>>>(part, vsum, out, 1.0f, 1);
    // iter 2: logits = u_hat . (v0+v1)
    caps_pass<1><<<grid, 256, 0, stream>>>(xbp, wbp, zp, vsum, part);
    squash_reduce<<<320, 256, 0, stream>>>(part, vsum, out, 1.0f, 2);
}